// Round 19
// baseline (923.021 us; speedup 1.0000x reference)
//
#include <hip/hip_runtime.h>
#include <hip/hip_bf16.h>

#define B_TOT 65536
#define WPT_FLOATS (64 * 32 * 128)  // 262144 floats = 1 MiB

// Round-19: revert to R17 split (fusion compiled to 84 VGPR + AGPR shuttle
// -> regressed). dist S5 re-tiled to the other register-budget corner:
// 8 dims x 8 rows per pass (q=4 batches). Each thread handles ALL its 8
// embedding dims (e = 2pp+{0,1,8,9,16,17,24,25}) in one pass -> each fv
// ds_read_b128 feeds 32 FMAs (was 16): LDS reads halve (2048->1024/thread);
// rj arrays vanish (all m finalized in-pass). Cost: WpT read 4x/block
// (R12->R16 deltas: LDS-halving ~ +64us, L2-doubling ~ -29us -> net ~+35).
// LDS 12.3KB; expected ~130 VGPR (4-wave tier).
// Bit-exact: per-(thread,e,row) dot ff-ascending xyzw; per-chain rj update
// m-ascending; S6 argmin semantics exact.

// ---------------- Kernel A: MLP (+ WpT staging prologue) ----------------
__global__ __launch_bounds__(256, 2) void udp_mlp(
    const float* __restrict__ obs, const float* __restrict__ act,
    const float* __restrict__ obs2, const float* __restrict__ rew,
    const float* __restrict__ W0, const float* __restrict__ b0,
    const float* __restrict__ W1, const float* __restrict__ b1,
    const float* __restrict__ W2, const float* __restrict__ b2,
    const float* __restrict__ Wp, float* __restrict__ WpT,
    float* __restrict__ out) {
  __shared__ __align__(16) float A_[5120];   // xs[32][160] 20KB
  __shared__ __align__(16) float Bb[8192];   // h1->h2 [32][256] 32KB
  const int t = threadIdx.x;
  const int blockRow = blockIdx.x * 32;

  float* out0 = out;                        // feat[:,0:32) stash
  float* out3 = out + (size_t)B_TOT * 34;   // feat[:,32:64) stash
  float* out4 = out + (size_t)B_TOT * 66;   // feat[:,64:128) stash

  // ---- S0: WpT staging slice (128 elems/block; 2048*128 = 262144) ----
  // WpT[idx], idx = e*8192 + f4*256 + n*4 + j <- Wp[(n*32+e)*128 + f4*4 + j]
  if (WpT != nullptr && t < 128) {
    const int idx = blockIdx.x * 128 + t;
    const int j  = idx & 3;
    const int n  = (idx >> 2) & 63;
    const int f4 = (idx >> 8) & 31;
    const int e  = idx >> 13;
    WpT[idx] = Wp[(n * 32 + e) * 128 + f4 * 4 + j];
  }

  // ---- S1: stage x = [obs | obs2-obs | act | rew] into A_ ----
  for (int i = t; i < 32 * 160; i += 256) {
    int r = i / 160, k = i - r * 160;
    int row = blockRow + r;
    float v;
    if (k < 64)        v = obs[row * 64 + k];
    else if (k < 128)  v = obs2[row * 64 + (k - 64)] - obs[row * 64 + (k - 64)];
    else if (k < 144)  v = act[row * 16 + (k - 128)];
    else if (k == 144) v = rew[row];
    else               v = 0.f;
    A_[i] = v;
  }
  __syncthreads();

  // ---- S2: layer 0 (145 -> 256). 4 neurons x 8 rows per thread ----
  {
    const int n4 = (t & 63) * 4;
    const int rbase = (t >> 6) * 8;  // wave-uniform
    float aA[8], aB[8], aC[8], aD[8];
#pragma unroll
    for (int r = 0; r < 8; ++r) { aA[r] = 0.f; aB[r] = 0.f; aC[r] = 0.f; aD[r] = 0.f; }
    const float4 bb = *(const float4*)&b0[n4];
    const float4 wt = *(const float4*)&W0[144 * 256 + n4];
    for (int k4 = 0; k4 < 144; k4 += 4) {
      const float4 w0 = *(const float4*)&W0[(k4 + 0) * 256 + n4];
      const float4 w1 = *(const float4*)&W0[(k4 + 1) * 256 + n4];
      const float4 w2 = *(const float4*)&W0[(k4 + 2) * 256 + n4];
      const float4 w3 = *(const float4*)&W0[(k4 + 3) * 256 + n4];
#pragma unroll
      for (int r = 0; r < 8; ++r) {
        const float4 xv = *(const float4*)&A_[(rbase + r) * 160 + k4];  // broadcast
        aA[r] = fmaf(xv.x, w0.x, aA[r]); aA[r] = fmaf(xv.y, w1.x, aA[r]);
        aA[r] = fmaf(xv.z, w2.x, aA[r]); aA[r] = fmaf(xv.w, w3.x, aA[r]);
        aB[r] = fmaf(xv.x, w0.y, aB[r]); aB[r] = fmaf(xv.y, w1.y, aB[r]);
        aB[r] = fmaf(xv.z, w2.y, aB[r]); aB[r] = fmaf(xv.w, w3.y, aB[r]);
        aC[r] = fmaf(xv.x, w0.z, aC[r]); aC[r] = fmaf(xv.y, w1.z, aC[r]);
        aC[r] = fmaf(xv.z, w2.z, aC[r]); aC[r] = fmaf(xv.w, w3.z, aC[r]);
        aD[r] = fmaf(xv.x, w0.w, aD[r]); aD[r] = fmaf(xv.y, w1.w, aD[r]);
        aD[r] = fmaf(xv.z, w2.w, aD[r]); aD[r] = fmaf(xv.w, w3.w, aD[r]);
      }
    }
#pragma unroll
    for (int r = 0; r < 8; ++r) {
      const float xt = A_[(rbase + r) * 160 + 144];
      aA[r] = fmaf(xt, wt.x, aA[r]); aB[r] = fmaf(xt, wt.y, aB[r]);
      aC[r] = fmaf(xt, wt.z, aC[r]); aD[r] = fmaf(xt, wt.w, aD[r]);
    }
#pragma unroll
    for (int r = 0; r < 8; ++r) {
      float4 v;
      v.x = aA[r] + bb.x; v.x = v.x > 0.f ? v.x : 0.01f * v.x;
      v.y = aB[r] + bb.y; v.y = v.y > 0.f ? v.y : 0.01f * v.y;
      v.z = aC[r] + bb.z; v.z = v.z > 0.f ? v.z : 0.01f * v.z;
      v.w = aD[r] + bb.w; v.w = v.w > 0.f ? v.w : 0.01f * v.w;
      *(float4*)&Bb[(rbase + r) * 256 + n4] = v;  // h1
    }
  }
  __syncthreads();

  // ---- S3: layer 1 (256 -> 256). h2 overwrites h1 (barrier before write) ----
  {
    const int n4 = (t & 63) * 4;
    const int rbase = (t >> 6) * 8;
    float aA[8], aB[8], aC[8], aD[8];
#pragma unroll
    for (int r = 0; r < 8; ++r) { aA[r] = 0.f; aB[r] = 0.f; aC[r] = 0.f; aD[r] = 0.f; }
    const float4 bb = *(const float4*)&b1[n4];
    for (int k4 = 0; k4 < 256; k4 += 4) {
      const float4 w0 = *(const float4*)&W1[(k4 + 0) * 256 + n4];
      const float4 w1 = *(const float4*)&W1[(k4 + 1) * 256 + n4];
      const float4 w2 = *(const float4*)&W1[(k4 + 2) * 256 + n4];
      const float4 w3 = *(const float4*)&W1[(k4 + 3) * 256 + n4];
#pragma unroll
      for (int r = 0; r < 8; ++r) {
        const float4 xv = *(const float4*)&Bb[(rbase + r) * 256 + k4];  // broadcast
        aA[r] = fmaf(xv.x, w0.x, aA[r]); aA[r] = fmaf(xv.y, w1.x, aA[r]);
        aA[r] = fmaf(xv.z, w2.x, aA[r]); aA[r] = fmaf(xv.w, w3.x, aA[r]);
        aB[r] = fmaf(xv.x, w0.y, aB[r]); aB[r] = fmaf(xv.y, w1.y, aB[r]);
        aB[r] = fmaf(xv.z, w2.y, aB[r]); aB[r] = fmaf(xv.w, w3.y, aB[r]);
        aC[r] = fmaf(xv.x, w0.z, aC[r]); aC[r] = fmaf(xv.y, w1.z, aC[r]);
        aC[r] = fmaf(xv.z, w2.z, aC[r]); aC[r] = fmaf(xv.w, w3.z, aC[r]);
        aD[r] = fmaf(xv.x, w0.w, aD[r]); aD[r] = fmaf(xv.y, w1.w, aD[r]);
        aD[r] = fmaf(xv.z, w2.w, aD[r]); aD[r] = fmaf(xv.w, w3.w, aD[r]);
      }
    }
    __syncthreads();  // all h1 reads done before any h2 write
#pragma unroll
    for (int r = 0; r < 8; ++r) {
      float4 v;
      v.x = aA[r] + bb.x; v.x = v.x > 0.f ? v.x : 0.01f * v.x;
      v.y = aB[r] + bb.y; v.y = v.y > 0.f ? v.y : 0.01f * v.y;
      v.z = aC[r] + bb.z; v.z = v.z > 0.f ? v.z : 0.01f * v.z;
      v.w = aD[r] + bb.w; v.w = v.w > 0.f ? v.w : 0.01f * v.w;
      *(float4*)&Bb[(rbase + r) * 256 + n4] = v;  // h2 (in place)
    }
  }
  __syncthreads();

  // ---- S4: layer 2 (256 -> 128). 4 neurons x 4 rows; feat -> global stash ----
  {
    const int n4 = (t & 31) * 4;
    const int rbase = (t >> 5) * 4;
    float aA[4], aB[4], aC[4], aD[4];
#pragma unroll
    for (int r = 0; r < 4; ++r) { aA[r] = 0.f; aB[r] = 0.f; aC[r] = 0.f; aD[r] = 0.f; }
    const float4 bb = *(const float4*)&b2[n4];
    for (int k4 = 0; k4 < 256; k4 += 4) {
      const float4 w0 = *(const float4*)&W2[(k4 + 0) * 128 + n4];
      const float4 w1 = *(const float4*)&W2[(k4 + 1) * 128 + n4];
      const float4 w2 = *(const float4*)&W2[(k4 + 2) * 128 + n4];
      const float4 w3 = *(const float4*)&W2[(k4 + 3) * 128 + n4];
#pragma unroll
      for (int r = 0; r < 4; ++r) {
        const float4 xv = *(const float4*)&Bb[(rbase + r) * 256 + k4];
        aA[r] = fmaf(xv.x, w0.x, aA[r]); aA[r] = fmaf(xv.y, w1.x, aA[r]);
        aA[r] = fmaf(xv.z, w2.x, aA[r]); aA[r] = fmaf(xv.w, w3.x, aA[r]);
        aB[r] = fmaf(xv.x, w0.y, aB[r]); aB[r] = fmaf(xv.y, w1.y, aB[r]);
        aB[r] = fmaf(xv.z, w2.y, aB[r]); aB[r] = fmaf(xv.w, w3.y, aB[r]);
        aC[r] = fmaf(xv.x, w0.z, aC[r]); aC[r] = fmaf(xv.y, w1.z, aC[r]);
        aC[r] = fmaf(xv.z, w2.z, aC[r]); aC[r] = fmaf(xv.w, w3.z, aC[r]);
        aD[r] = fmaf(xv.x, w0.w, aD[r]); aD[r] = fmaf(xv.y, w1.w, aD[r]);
        aD[r] = fmaf(xv.z, w2.w, aD[r]); aD[r] = fmaf(xv.w, w3.w, aD[r]);
      }
    }
#pragma unroll
    for (int r = 0; r < 4; ++r) {
      float4 v;
      v.x = aA[r] + bb.x; v.x = v.x > 0.f ? v.x : 0.01f * v.x;
      v.y = aB[r] + bb.y; v.y = v.y > 0.f ? v.y : 0.01f * v.y;
      v.z = aC[r] + bb.z; v.z = v.z > 0.f ? v.z : 0.01f * v.z;
      v.w = aD[r] + bb.w; v.w = v.w > 0.f ? v.w : 0.01f * v.w;
      const size_t row = (size_t)blockRow + rbase + r;
      if (n4 < 32)      *(float4*)&out0[row * 32 + n4] = v;
      else if (n4 < 64) *(float4*)&out3[row * 32 + (n4 - 32)] = v;
      else              *(float4*)&out4[row * 64 + (n4 - 64)] = v;
    }
  }
}

// ---------------- Kernel B: projection + distance + outputs ----------------
// q=4 batches of 8 rows; S5 = 8 dims x 8 rows in ONE pass (all m merged).
// COAL=1: coalesced WpT; COAL=0: direct-Wp fallback.
template <int COAL>
__global__ __launch_bounds__(256, 2) void udp_dist(
    const float* __restrict__ Wp, const float* __restrict__ WpT,
    const float* __restrict__ emb, const float* __restrict__ sigma,
    float* __restrict__ out) {
  __shared__ __align__(16) float Fb[1024];   // feat batch [8][128] 4KB
  __shared__ __align__(16) float P_[2048];   // psum batch [8][4][64] 8KB
  __shared__ float idxArr[8];
  const int t = threadIdx.x;
  const int blockRow = blockIdx.x * 32;

  float* out0 = out;                        // chosen_embedding (B,32) [feat stash 0:32]
  float* out1 = out + (size_t)B_TOT * 32;   // chosen_dist (B,1)
  float* out2 = out + (size_t)B_TOT * 33;   // idx (B,1) as float
  float* out3 = out + (size_t)B_TOT * 34;   // chosen_mean (B,32) [feat stash 32:64]
  float* out4 = out + (size_t)B_TOT * 66;   // distance (B,64)  [feat stash 64:128]

  const int n = t & 63, pp = t >> 6;
  const float* eb = emb + n * 32;

#pragma unroll 1
  for (int q = 0; q < 4; ++q) {
    const int rbase = q * 8;

    // ---- F1: load feat stash rows [rbase, rbase+8) -> Fb (256 float4s) ----
    {
      const int r = t >> 5, c4 = (t & 31) * 4;
      const size_t row = (size_t)blockRow + rbase + r;
      float4 v;
      if (c4 < 32)      v = *(const float4*)&out0[row * 32 + c4];
      else if (c4 < 64) v = *(const float4*)&out3[row * 32 + (c4 - 32)];
      else              v = *(const float4*)&out4[row * 64 + (c4 - 64)];
      *(float4*)&Fb[r * 128 + c4] = v;
    }
    __syncthreads();

    // ---- S5: ALL 8 dims of this thread x 8 rows, one pass ----
    // dims d=0..7: e_d = 2pp + (d&1) + 8*(d>>1)  (even d -> chain j=2pp at
    // m=d>>1; odd d -> chain j=2pp+1). Each fv read feeds 32 FMAs.
    // Per-(thread,e,row) dot: ff-ascending xyzw. Chain updates m-ascending.
    {
      const float *p[8];
#pragma unroll
      for (int d = 0; d < 8; ++d) {
        const int e = 2 * pp + (d & 1) + 8 * (d >> 1);
        if (COAL) p[d] = WpT + e * 8192 + n * 4;
        else      p[d] = Wp + ((size_t)n * 32 + e) * 128;
      }
      const int WSTR = COAL ? 256 : 4;
      float a[8][8];
#pragma unroll
      for (int d = 0; d < 8; ++d)
#pragma unroll
        for (int r = 0; r < 8; ++r) a[d][r] = 0.f;
      for (int ff = 0; ff < 32; ++ff) {
        float4 w[8];
#pragma unroll
        for (int d = 0; d < 8; ++d) w[d] = *(const float4*)(p[d] + ff * WSTR);
#pragma unroll
        for (int r = 0; r < 8; ++r) {
          const float4 fv = *(const float4*)&Fb[r * 128 + ff * 4];  // broadcast
#pragma unroll
          for (int d = 0; d < 8; ++d) {
            a[d][r] = fmaf(fv.x, w[d].x, a[d][r]);
            a[d][r] = fmaf(fv.y, w[d].y, a[d][r]);
            a[d][r] = fmaf(fv.z, w[d].z, a[d][r]);
            a[d][r] = fmaf(fv.w, w[d].w, a[d][r]);
          }
        }
      }
      float em[8];
#pragma unroll
      for (int d = 0; d < 8; ++d) em[d] = eb[2 * pp + (d & 1) + 8 * (d >> 1)];
#pragma unroll
      for (int r = 0; r < 8; ++r) {
        // chain j=2pp: dims d=0,2,4,6 (m=0..3 ascending); j=2pp+1: d=1,3,5,7
        float rj0 = 0.f, rj1 = 0.f, dd;
        dd = a[0][r] - em[0]; rj0 = fmaf(dd, dd, rj0);
        dd = a[1][r] - em[1]; rj1 = fmaf(dd, dd, rj1);
        dd = a[2][r] - em[2]; rj0 = fmaf(dd, dd, rj0);
        dd = a[3][r] - em[3]; rj1 = fmaf(dd, dd, rj1);
        dd = a[4][r] - em[4]; rj0 = fmaf(dd, dd, rj0);
        dd = a[5][r] - em[5]; rj1 = fmaf(dd, dd, rj1);
        dd = a[6][r] - em[6]; rj0 = fmaf(dd, dd, rj0);
        dd = a[7][r] - em[7]; rj1 = fmaf(dd, dd, rj1);
        const int gr = rbase + r;
        // psum P_[r][pp][(n+gr)&63]: write 2-way (free), S6 read conflict-free
        P_[r * 256 + pp * 64 + ((n + gr) & 63)] = rj0 + rj1;
      }
    }
    __syncthreads();

    // ---- S6: distance + argmin, parallel (t<64): r=t>>3, k=t&7 ----
    // nn in [8k,8k+8) ascending (local first-min), then 3-step shfl_xor
    // with smaller-index tie-break == np.argmin first-min exactly.
    if (t < 64) {
      const int r = t >> 3, k = t & 7;
      const int gr = rbase + r;
      float best = 1e30f;
      int bi = 0;
      for (int u = 0; u < 8; ++u) {
        const int nn = 8 * k + u;
        const int nr = (nn + gr) & 63;
        const float p0 = P_[r * 256 + 0 * 64 + nr];
        const float p1 = P_[r * 256 + 1 * 64 + nr];
        const float p2 = P_[r * 256 + 2 * 64 + nr];
        const float p3 = P_[r * 256 + 3 * 64 + nr];
        float s = (p0 + p1) + (p2 + p3);  // numpy pairwise combine
        float mean = s / 32.0f;           // exact (pow2)
        float sg = sigma[nn];
        float den = 2.0f * sg * sg;
        float dist = expf((-mean) / den);
        P_[r * 256 + nr] = dist;          // swizzled dist store
        if (dist < best) { best = dist; bi = nn; }  // local first-min
      }
#pragma unroll
      for (int m = 1; m < 8; m <<= 1) {
        const float ob = __shfl_xor(best, m);
        const int obi = __shfl_xor(bi, m);
        if (ob < best || (ob == best && obi < bi)) { best = ob; bi = obi; }
      }
      if (k == 0) {
        const size_t row = (size_t)blockRow + gr;
        idxArr[r] = (float)bi;
        out1[row] = best;
        out2[row] = (float)bi;
      }
    }
    __syncthreads();

    // ---- S7a: distance matrix out for batch (undo swizzle), 8*64=512 ----
    for (int i = t; i < 512; i += 256) {
      const int r = i >> 6, nn = i & 63;
      const int gr = rbase + r;
      out4[(size_t)(blockRow + gr) * 64 + nn] = P_[r * 256 + ((nn + gr) & 63)];
    }
    // ---- S7b: chosen embedding + chosen mean for batch, 8*32=256 ----
    {
      const int r = t >> 5, e = t & 31;
      const int bi = (int)idxArr[r];
      const float* wrow = Wp + (bi * 32 + e) * 128;
      float acc = 0.f;
      for (int f4 = 0; f4 < 128; f4 += 4) {
        const float4 wv = *(const float4*)(wrow + f4);
        const float4 fv = *(const float4*)&Fb[r * 128 + f4];
        acc = fmaf(fv.x, wv.x, acc);
        acc = fmaf(fv.y, wv.y, acc);
        acc = fmaf(fv.z, wv.z, acc);
        acc = fmaf(fv.w, wv.w, acc);
      }
      const size_t row = (size_t)blockRow + rbase + r;
      out0[row * 32 + e] = acc;
      out3[row * 32 + e] = emb[bi * 32 + e];
    }
    __syncthreads();  // Fb/P_/idxArr reused by next batch
  }
}

extern "C" void kernel_launch(void* const* d_in, const int* in_sizes, int n_in,
                              void* d_out, int out_size, void* d_ws, size_t ws_size,
                              hipStream_t stream) {
  const float* obs   = (const float*)d_in[0];
  const float* act   = (const float*)d_in[1];
  const float* obs2  = (const float*)d_in[2];
  const float* rew   = (const float*)d_in[3];
  const float* W0    = (const float*)d_in[4];
  const float* b0    = (const float*)d_in[5];
  const float* W1    = (const float*)d_in[6];
  const float* b1    = (const float*)d_in[7];
  const float* W2    = (const float*)d_in[8];
  const float* b2    = (const float*)d_in[9];
  const float* Wp    = (const float*)d_in[10];
  const float* e_emb = (const float*)d_in[11];
  const float* sigma = (const float*)d_in[12];

  const bool coal = (d_ws != nullptr) && (ws_size >= WPT_FLOATS * sizeof(float));
  float* WpT = coal ? (float*)d_ws : nullptr;

  udp_mlp<<<dim3(B_TOT / 32), dim3(256), 0, stream>>>(
      obs, act, obs2, rew, W0, b0, W1, b1, W2, b2, Wp, WpT, (float*)d_out);
  if (coal) {
    udp_dist<1><<<dim3(B_TOT / 32), dim3(256), 0, stream>>>(
        Wp, WpT, e_emb, sigma, (float*)d_out);
  } else {
    udp_dist<0><<<dim3(B_TOT / 32), dim3(256), 0, stream>>>(
        Wp, Wp, e_emb, sigma, (float*)d_out);
  }
}